// Round 9
// baseline (1195.263 us; speedup 1.0000x reference)
//
#include <hip/hip_runtime.h>

// TemporalAttentionDecoder_three_step: B=512, T=64, M=P=256. in f32, out f32.
// R8: 1189us. Coalesced f16 k-blocked weights + fdot2 worked. Remaining wall:
//     per-CU weight ingress 1.5MB/step (2 WGs x 768KB) ~ 61% of L2 ceiling.
// R9: 2 batch rows per 512-thr WG (256 WGs = 1/CU, LDS ~93KB forces
//     exclusivity): each weight block loaded ONCE, dotted vs BOTH rows ->
//     786KB/CU/step (2x less). E dropped from LDS -> E f16 in ws (prep),
//     B2 reads columns (coalesced per-wave, L2-hot). Softmax register-
//     resident per wave (redundant per-wave compute, shfl broadcast in B2)
//     -> 5 barriers/step.
// Per step: stream (Wd kh-split + Whh, 6 dots/thr, shared weight loads) |
//           x1 combine | B1 tanh/l | SM+B2+ytil-red (fused) | gates.

typedef unsigned short u16;
typedef unsigned int u32;
typedef _Float16 half_t;
typedef half_t h2 __attribute__((ext_vector_type(2)));

#define BB 512
#define TT 64
#define MM 256
#define PP 256
#define YS 264   // y1l row stride (u16); measured conflict-free (R6-R8)

// ws layout (u16):
//   weights k-blocked n-major [kb][n][8]:
//     WdT8 [64][256][8] @0 | WhhT8 [32][1024][8] @131072 | WyT8 [64][256][8] @393216
//   E16 row-major (B,T,M) f16 @524288 (8388608 elems)
#define WD16_OFF  0
#define WHH16_OFF 131072
#define WY16_OFF  393216
#define WQ_ELEMS  524288
#define E16_OFF   524288
#define E16_ELEMS (BB * TT * MM)
#define WS_ELEMS  (WQ_ELEMS + E16_ELEMS)
#define WS_BYTES  (WS_ELEMS * 2)

struct H8 { h2 p[4]; };   // 16B = 8 f16

#if defined(__has_builtin)
#if __has_builtin(__builtin_amdgcn_fdot2)
#define FDOT2(a, b, c) __builtin_amdgcn_fdot2((a), (b), (c), false)
#endif
#endif
#ifndef FDOT2
__device__ __forceinline__ float FDOT2(h2 a, h2 b, float c) {
  return c + (float)a[0] * (float)b[0] + (float)a[1] * (float)b[1];
}
#endif

__device__ __forceinline__ float dot8(const H8 w, const H8 a, float acc) {
  acc = FDOT2(w.p[0], a.p[0], acc);
  acc = FDOT2(w.p[1], a.p[1], acc);
  acc = FDOT2(w.p[2], a.p[2], acc);
  acc = FDOT2(w.p[3], a.p[3], acc);
  return acc;
}
__device__ __forceinline__ u16 f2h(float f) {
  union { half_t h; u16 u; } x; x.h = (half_t)f; return x.u;
}
__device__ __forceinline__ void unpackH8(const H8 v, float f[8]) {
#pragma unroll
  for (int i = 0; i < 8; ++i) f[i] = (float)v.p[i >> 1][i & 1];
}
__device__ __forceinline__ void ldf8(const float* p, float f[8]) {
  float4 a = *(const float4*)p;
  float4 b = *(const float4*)(p + 4);
  f[0]=a.x; f[1]=a.y; f[2]=a.z; f[3]=a.w;
  f[4]=b.x; f[5]=b.y; f[6]=b.z; f[7]=b.w;
}
__device__ __forceinline__ float tanh_fast(float x) {
  float e = __builtin_amdgcn_exp2f(x * 2.885390081777927f);
  return 1.0f - 2.0f * __builtin_amdgcn_rcpf(1.0f + e);
}
__device__ __forceinline__ float sigmoid_fast(float x) {
  float e = __builtin_amdgcn_exp2f(x * -1.4426950408889634f);
  return __builtin_amdgcn_rcpf(1.0f + e);
}

// ---- prep: weights f32 -> f16 k-blocked n-major ----
__global__ __launch_bounds__(256) void prep_w(
    const float* __restrict__ Wd, const float* __restrict__ Whh,
    const float* __restrict__ Wy, u16* __restrict__ o) {
  int i = blockIdx.x * 256 + threadIdx.x;   // 0..524287
  float v;
  if (i < WHH16_OFF) {
    int ki = i & 7, n = (i >> 3) & 255, kb = i >> 11;
    v = Wd[n * 512 + kb * 8 + ki];
  } else if (i < WY16_OFF) {
    int r = i - WHH16_OFF;
    int ki = r & 7, n = (r >> 3) & 1023, kb = r >> 13;
    v = Whh[n * 256 + kb * 8 + ki];
  } else {
    int r = i - WY16_OFF;
    int ki = r & 7, n = (r >> 3) & 255, kb = r >> 11;
    v = Wy[n * 512 + kb * 8 + ki];
  }
  o[i] = f2h(v);
}

// ---- prep: E f32 -> f16 row-major ----
__global__ __launch_bounds__(256) void prep_e(
    const float* __restrict__ E, u16* __restrict__ o) {
  int i = blockIdx.x * 256 + threadIdx.x;
  o[E16_OFF + i] = f2h(E[i]);
}

template <int WQ>
__global__ __launch_bounds__(512, 2) void scan_kernel(
    const float* __restrict__ E,      // (B,T,M) f32
    const float* __restrict__ yin,    // (B,T,1)
    const float* __restrict__ tar,    // (B,2)
    const int*   __restrict__ train,  // (1)
    const void*  __restrict__ Wd_q,   // WQ1: k-blocked f16 | WQ0: f32 row-major
    const float* __restrict__ Wd_b,
    const float* __restrict__ Ud_w,   // (256,256) f32
    const float* __restrict__ vd_w,
    const float* __restrict__ wt_w,   // (257)
    const float* __restrict__ wt_b,
    const void*  __restrict__ Wy_q,
    const float* __restrict__ Wy_b,
    const float* __restrict__ vy_w,
    const float* __restrict__ vy_b,
    const float* __restrict__ Wih,    // (1024)
    const void*  __restrict__ Whh_q,
    const float* __restrict__ bih,
    const float* __restrict__ bhh,
    const u16*   __restrict__ E16,    // f16 (B,T,M) in ws (WQ1 only)
    float* __restrict__ out)          // (3*B)
{
  __shared__ __align__(16) u16   y1l[2][TT * YS];   // 67.6KB f16 y1, padded
  __shared__ __align__(16) u32   hs16[2 * 256];     // row: h pairs[0,128) c[128,256)
  __shared__ __align__(16) u32   ctx16p[2 * 128];   // ct f16 pairs per row
  __shared__ __align__(16) float gbuf[2][1024];     // LSTM matvec partials
  __shared__ __align__(16) float part[2][2][256];   // [kh][row][n]
  __shared__ __align__(16) float x1s[2][MM];
  __shared__ __align__(16) float ctx[2][MM];
  __shared__ __align__(16) float lpart[2][4][TT];
  __shared__ float red[2][4];
  __shared__ float sc_head[2];

  const int tid  = threadIdx.x;        // 0..511
  const int half = tid >> 8;           // batch row within WG
  const int j    = tid & 255;
  const int wv   = (tid >> 6) & 3;     // wave-quarter within half
  const int lane = tid & 63;
  const int b    = blockIdx.x * 2 + half;

  hs16[tid] = 0;
  float creg = 0.f;

  // ---- y1 into LDS: thread (half, j) computes column j for all t ----
  {
    const float* __restrict__ Eb = E + (size_t)b * TT * MM;
    const float* __restrict__ Uj = Ud_w + (size_t)j * MM;
    for (int t0 = 0; t0 < TT; t0 += 16) {
      float acc[16];
#pragma unroll
      for (int i = 0; i < 16; ++i) acc[i] = 0.f;
      for (int m0 = 0; m0 < MM; m0 += 8) {
        float w[8]; ldf8(Uj + m0, w);
#pragma unroll
        for (int tt = 0; tt < 16; ++tt) {
          float e[8]; ldf8(Eb + (size_t)(t0 + tt) * MM + m0, e);
#pragma unroll
          for (int mm = 0; mm < 8; ++mm) acc[tt] = fmaf(e[mm], w[mm], acc[tt]);
        }
      }
#pragma unroll
      for (int tt = 0; tt < 16; ++tt)
        y1l[half][(t0 + tt) * YS + j] = f2h(acc[tt]);
    }
  }
  __syncthreads();

  // ---- Whh @ h for BOTH rows -> gbuf (weight block loaded once) ----
  auto whh_mv = [&]() {
    float b00 = 0.f, b01 = 0.f, b10 = 0.f, b11 = 0.f;
    if (WQ) {
      const u16* p1 = (const u16*)Whh_q + (size_t)tid * 8;
      const u16* p2 = p1 + 512 * 8;
#pragma unroll 4
      for (int kb = 0; kb < 32; ++kb) {
        H8 h0 = *(const H8*)&hs16[kb * 4];
        H8 h1 = *(const H8*)&hs16[256 + kb * 4];
        H8 w1 = *(const H8*)p1; p1 += 8192;
        H8 w2 = *(const H8*)p2; p2 += 8192;
        b00 = dot8(w1, h0, b00);
        b01 = dot8(w1, h1, b01);
        b10 = dot8(w2, h0, b10);
        b11 = dot8(w2, h1, b11);
      }
    } else {
      const float* q1 = (const float*)Whh_q + (size_t)tid * 256;
      const float* q2 = q1 + 512 * 256;
#pragma unroll 2
      for (int kb = 0; kb < 32; ++kb) {
        H8 h0 = *(const H8*)&hs16[kb * 4];
        H8 h1 = *(const H8*)&hs16[256 + kb * 4];
        float f0[8], f1[8]; unpackH8(h0, f0); unpackH8(h1, f1);
        float w1[8], w2[8];
        ldf8(q1 + kb * 8, w1);
        ldf8(q2 + kb * 8, w2);
#pragma unroll
        for (int i = 0; i < 8; ++i) {
          b00 = fmaf(f0[i], w1[i], b00);
          b01 = fmaf(f1[i], w1[i], b01);
          b10 = fmaf(f0[i], w2[i], b10);
          b11 = fmaf(f1[i], w2[i], b11);
        }
      }
    }
    gbuf[0][tid] = b00;       gbuf[1][tid] = b01;
    gbuf[0][tid + 512] = b10; gbuf[1][tid + 512] = b11;
  };

  // ---- gates for (half, j): torch order i,f,g,o; h,c -> hs16 f16 ----
  auto gates_apply = [&](float ytil) {
    float g0 = gbuf[half][j]       + ytil * Wih[j]       + bih[j]       + bhh[j];
    float g1 = gbuf[half][j + 256] + ytil * Wih[j + 256] + bih[j + 256] + bhh[j + 256];
    float g2 = gbuf[half][j + 512] + ytil * Wih[j + 512] + bih[j + 512] + bhh[j + 512];
    float g3 = gbuf[half][j + 768] + ytil * Wih[j + 768] + bih[j + 768] + bhh[j + 768];
    float c = sigmoid_fast(g1) * creg + sigmoid_fast(g0) * tanh_fast(g2);
    float h = sigmoid_fast(g3) * tanh_fast(c);
    creg = c;
    u16* hsu = (u16*)hs16;
    hsu[half * 512 + j]       = f2h(h);
    hsu[half * 512 + 256 + j] = f2h(c);
  };

  // ---- head: both rows; weight block loaded once ----
  auto head_store = [&](int outIdx) {
    float p0 = 0.f, p1 = 0.f;
    if (WQ) {
      // kh=half: 0 -> h seg (kb 0..31, act hs16), 1 -> ct seg (kb 32..63, ctx16p)
      const u16* pw = (const u16*)Wy_q + (size_t)half * 32 * 2048 + (size_t)j * 8;
      const u32* a0 = half ? &ctx16p[0] : &hs16[0];
      const u32* a1 = half ? &ctx16p[128] : &hs16[256];
#pragma unroll 4
      for (int kb = 0; kb < 32; ++kb) {
        H8 w = *(const H8*)pw; pw += 2048;
        p0 = dot8(w, *(const H8*)&a0[kb * 4], p0);
        p1 = dot8(w, *(const H8*)&a1[kb * 4], p1);
      }
    } else {
      const float* pw = (const float*)Wy_q + (size_t)j * 512 + half * 256;
      for (int kb = 0; kb < 32; ++kb) {
        float w[8]; ldf8(pw + kb * 8, w);
        if (half) {
#pragma unroll
          for (int i = 0; i < 8; ++i) {
            p0 = fmaf(ctx[0][kb * 8 + i], w[i], p0);
            p1 = fmaf(ctx[1][kb * 8 + i], w[i], p1);
          }
        } else {
          H8 h0 = *(const H8*)&hs16[kb * 4];
          H8 h1 = *(const H8*)&hs16[256 + kb * 4];
          float f0[8], f1[8]; unpackH8(h0, f0); unpackH8(h1, f1);
#pragma unroll
          for (int i = 0; i < 8; ++i) {
            p0 = fmaf(f0[i], w[i], p0);
            p1 = fmaf(f1[i], w[i], p1);
          }
        }
      }
    }
    part[half][0][j] = p0;
    part[half][1][j] = p1;
    __syncthreads();
    {
      float hp = part[0][half][j] + part[1][half][j] + Wy_b[j];
      float pp = hp * vy_w[j];
#pragma unroll
      for (int off = 32; off; off >>= 1) pp += __shfl_xor(pp, off, 64);
      if (lane == 0) red[half][wv] = pp;
    }
    __syncthreads();
    if (j == 0) {
      float o = red[half][0] + red[half][1] + red[half][2] + red[half][3]
              + vy_b[0];
      out[(size_t)outIdx * BB + b] = o;
      sc_head[half] = o;
    }
    __syncthreads();
  };

  // ================= scan over T steps =================
  for (int step = 0; step < TT; ++step) {
    // ---- stream: Wd (kh=half split) + Whh, every weight block x 2 rows ----
    {
      float ax0 = 0.f, ax1 = 0.f;               // x1 partials rows 0/1
      float b00 = 0.f, b01 = 0.f, b10 = 0.f, b11 = 0.f;
      if (WQ) {
        const u16* pd = (const u16*)Wd_q + (size_t)half * 32 * 2048 + (size_t)j * 8;
        const u16* p1 = (const u16*)Whh_q + (size_t)tid * 8;
        const u16* p2 = p1 + 512 * 8;
        const int ao = half * 128;              // h seg (0) or c seg (128)
#pragma unroll 4
        for (int kb = 0; kb < 32; ++kb) {
          H8 h0 = *(const H8*)&hs16[kb * 4];
          H8 h1 = *(const H8*)&hs16[256 + kb * 4];
          H8 a0 = *(const H8*)&hs16[ao + kb * 4];
          H8 a1 = *(const H8*)&hs16[256 + ao + kb * 4];
          H8 wd = *(const H8*)pd; pd += 2048;
          H8 w1 = *(const H8*)p1; p1 += 8192;
          H8 w2 = *(const H8*)p2; p2 += 8192;
          ax0 = dot8(wd, a0, ax0);
          ax1 = dot8(wd, a1, ax1);
          b00 = dot8(w1, h0, b00);
          b01 = dot8(w1, h1, b01);
          b10 = dot8(w2, h0, b10);
          b11 = dot8(w2, h1, b11);
        }
      } else {
        const float* pd = (const float*)Wd_q + (size_t)j * 512 + half * 256;
        const float* q1 = (const float*)Whh_q + (size_t)tid * 256;
        const float* q2 = q1 + 512 * 256;
        const int ao = half * 128;
#pragma unroll 2
        for (int kb = 0; kb < 32; ++kb) {
          H8 h0 = *(const H8*)&hs16[kb * 4];
          H8 h1 = *(const H8*)&hs16[256 + kb * 4];
          H8 c0 = *(const H8*)&hs16[ao + kb * 4];
          H8 c1 = *(const H8*)&hs16[256 + ao + kb * 4];
          float f0[8], f1[8], e0[8], e1[8];
          unpackH8(h0, f0); unpackH8(h1, f1); unpackH8(c0, e0); unpackH8(c1, e1);
          float wd[8], w1[8], w2[8];
          ldf8(pd + kb * 8, wd);
          ldf8(q1 + kb * 8, w1);
          ldf8(q2 + kb * 8, w2);
#pragma unroll
          for (int i = 0; i < 8; ++i) {
            ax0 = fmaf(e0[i], wd[i], ax0);
            ax1 = fmaf(e1[i], wd[i], ax1);
            b00 = fmaf(f0[i], w1[i], b00);
            b01 = fmaf(f1[i], w1[i], b01);
            b10 = fmaf(f0[i], w2[i], b10);
            b11 = fmaf(f1[i], w2[i], b11);
          }
        }
      }
      part[half][0][j] = ax0;
      part[half][1][j] = ax1;
      gbuf[0][tid] = b00;       gbuf[1][tid] = b01;
      gbuf[0][tid + 512] = b10; gbuf[1][tid + 512] = b11;
    }
    __syncthreads();
    x1s[half][j] = part[0][half][j] + part[1][half][j] + Wd_b[j];
    __syncthreads();

    // ---- B1: l[t] quarter-partials; thread = (half, q=wv, t=lane) ----
    {
      const u16* __restrict__ yrow = &y1l[half][lane * YS + wv * 64];
      const float* __restrict__ xp = &x1s[half][wv * 64];
      const float* __restrict__ vp = vd_w + wv * 64;
      float lp = 0.f;
#pragma unroll 2
      for (int m0 = 0; m0 < 64; m0 += 8) {
        H8 yv = *(const H8*)(yrow + m0);
        float yf[8]; unpackH8(yv, yf);
        float xf[8]; ldf8(xp + m0, xf);
        float vf[8]; ldf8(vp + m0, vf);
#pragma unroll
        for (int mm = 0; mm < 8; ++mm) {
          float z = tanh_fast(xf[mm] + yf[mm]);
          lp = fmaf(z, vf[mm], lp);
        }
      }
      lpart[half][wv][lane] = lp;
    }
    __syncthreads();

    // ---- softmax (register, per wave) + B2 + ytil partial (fused) ----
    float ctv;
    {
      float l = lpart[half][0][lane] + lpart[half][1][lane]
              + lpart[half][2][lane] + lpart[half][3][lane];
      float mx = l;
#pragma unroll
      for (int off = 32; off; off >>= 1) mx = fmaxf(mx, __shfl_xor(mx, off, 64));
      float e = __builtin_amdgcn_exp2f((l - mx) * 1.4426950408889634f);
      float sm = e;
#pragma unroll
      for (int off = 32; off; off >>= 1) sm += __shfl_xor(sm, off, 64);
      float beta = e * __builtin_amdgcn_rcpf(sm);   // lane t's beta

      // B2: ct[j] = sum_t beta[t] * E16[b][t][j]
      float acc = 0.f;
      if (WQ) {
        const half_t* __restrict__ ep = (const half_t*)E16 + (size_t)b * TT * MM + j;
#pragma unroll 8
        for (int t = 0; t < TT; ++t) {
          float bt = __shfl(beta, t, 64);
          acc = fmaf(bt, (float)ep[(size_t)t * MM], acc);
        }
      } else {
        const float* __restrict__ ep = E + (size_t)b * TT * MM + j;
#pragma unroll 8
        for (int t = 0; t < TT; ++t) {
          float bt = __shfl(beta, t, 64);
          acc = fmaf(bt, ep[(size_t)t * MM], acc);
        }
      }
      ctv = acc;
      ctx[half][j] = acc;
      ((u16*)ctx16p)[half * 256 + j] = f2h(acc);

      float p = ctv * wt_w[j];
#pragma unroll
      for (int off = 32; off; off >>= 1) p += __shfl_xor(p, off, 64);
      if (lane == 0) red[half][wv] = p;
    }
    __syncthreads();

    // ---- gates ----
    {
      float ytil = red[half][0] + red[half][1] + red[half][2] + red[half][3]
                 + yin[(size_t)b * TT + step] * wt_w[MM] + wt_b[0];
      gates_apply(ytil);
    }
    __syncthreads();
  }

  // ================= finals =================
  float ctdot;
  {
    float p = ctx[half][j] * wt_w[j];
#pragma unroll
    for (int off = 32; off; off >>= 1) p += __shfl_xor(p, off, 64);
    if (lane == 0) red[half][wv] = p;
    __syncthreads();
    ctdot = red[half][0] + red[half][1] + red[half][2] + red[half][3];
  }

  head_store(0);  // y_Tp1 (sc_head[half] holds it for train==0 feedback)

  const int tr = train[0];
  for (int e = 0; e < 2; ++e) {
    float inp = tr ? tar[(size_t)b * 2 + e] : sc_head[half];
    float ytil = ctdot + inp * wt_w[MM] + wt_b[0];
    whh_mv();
    __syncthreads();
    gates_apply(ytil);
    __syncthreads();
    head_store(1 + e);
  }
}

extern "C" void kernel_launch(void* const* d_in, const int* in_sizes, int n_in,
                              void* d_out, int out_size, void* d_ws, size_t ws_size,
                              hipStream_t stream) {
  const float* E     = (const float*)d_in[0];
  const float* yin   = (const float*)d_in[1];
  const float* tar   = (const float*)d_in[2];
  const int*   train = (const int*)d_in[3];
  const float* Wd_w  = (const float*)d_in[4];
  const float* Wd_b  = (const float*)d_in[5];
  const float* Ud_w  = (const float*)d_in[6];
  const float* vd_w  = (const float*)d_in[7];
  const float* wt_w  = (const float*)d_in[8];
  const float* wt_b  = (const float*)d_in[9];
  const float* Wy_w  = (const float*)d_in[10];
  const float* Wy_b  = (const float*)d_in[11];
  const float* vy_w  = (const float*)d_in[12];
  const float* vy_b  = (const float*)d_in[13];
  const float* Wih   = (const float*)d_in[14];
  const float* Whh   = (const float*)d_in[15];
  const float* bih   = (const float*)d_in[16];
  const float* bhh   = (const float*)d_in[17];

  float* out = (float*)d_out;

  if (ws_size >= (size_t)WS_BYTES) {
    u16* wq = (u16*)d_ws;
    prep_w<<<dim3(WQ_ELEMS / 256), dim3(256), 0, stream>>>(Wd_w, Whh, Wy_w, wq);
    prep_e<<<dim3(E16_ELEMS / 256), dim3(256), 0, stream>>>(E, wq);
    scan_kernel<1><<<dim3(BB / 2), dim3(512), 0, stream>>>(
        E, yin, tar, train, wq + WD16_OFF, Wd_b, Ud_w, vd_w, wt_w, wt_b,
        wq + WY16_OFF, Wy_b, vy_w, vy_b, Wih, wq + WHH16_OFF, bih, bhh,
        wq + E16_OFF, out);
  } else {
    scan_kernel<0><<<dim3(BB / 2), dim3(512), 0, stream>>>(
        E, yin, tar, train, Wd_w, Wd_b, Ud_w, vd_w, wt_w, wt_b,
        Wy_w, Wy_b, vy_w, vy_b, Wih, Whh, bih, bhh, (const u16*)nullptr, out);
  }

  (void)in_sizes; (void)n_in; (void)out_size;
}